// Round 1
// baseline (673.444 us; speedup 1.0000x reference)
//
#include <hip/hip_runtime.h>
#include <stdint.h>
#include <math.h>

// Problem dims
#define BDIM 8192
#define TDIM 8192
#define FDIM 768
#define PDIM 512
#define HDIM 1024
#define NEXP 4
#define NCAT 5376  // 4*1024 (experts) + 1024 (ds) + 256 (router)

using short4v = __attribute__((ext_vector_type(4))) short;
using short8 = __attribute__((ext_vector_type(8))) short;
using f32x4  = __attribute__((ext_vector_type(4))) float;

__device__ __forceinline__ short f2bf(float f) {
  uint32_t u = __builtin_bit_cast(uint32_t, f);
  u += 0x7fffu + ((u >> 16) & 1u);   // RNE
  return (short)(u >> 16);
}
__device__ __forceinline__ float bf2f(short s) {
  uint32_t u = ((uint32_t)(uint16_t)s) << 16;
  return __builtin_bit_cast(float, u);
}
__device__ __forceinline__ float gelu_exact(float x) {
  return 0.5f * x * (1.0f + erff(x * 0.70710678118654752f));
}

#define GLDS(gp, lp) __builtin_amdgcn_global_load_lds( \
    (const __attribute__((address_space(1))) void*)(gp), \
    (__attribute__((address_space(3))) void*)(lp), 16, 0, 0)

// ---------------------------------------------------------------------------
// 256x256-tile deep-pipelined GEMM: C[M,N] = A[M,K] @ B[N,K]^T, bf16 inputs.
// 512 threads = 8 waves (2 M x 4 N), per-wave 128x64 output, BK=32.
// 4-deep LDS ring of K-tiles (128 KiB), staging leads compute by 3 tiles ->
// counted s_waitcnt vmcnt(8) at tile boundaries (never a full drain in the
// steady state). LDS XOR-swizzle (S ^= ((S>>7)&7)<<4) applied on the global
// SOURCE address of global_load_lds (dest stays linear) and on the ds_read
// offsets -> bank-conflict-free 16-lane column reads.
// MODE 0: +bias[col], gelu, store bf16.  MODE 2: *scale, store f32.
// ---------------------------------------------------------------------------
template <int MODE>
__global__ __launch_bounds__(512, 2)
void gemm256(const short* __restrict__ A, int lda,
             const short* __restrict__ B, int ldb,
             void* __restrict__ C, int ldc, int K,
             const float* __restrict__ bias,
             const float* __restrict__ scale_ptr)
{
  __shared__ short lds_s[65536];  // 4 tiles x (A 256x32 + B 256x32) shorts = 128 KiB
  const int t    = threadIdx.x;
  const int lane = t & 63;
  const int wave = t >> 6;
  const int wr   = wave >> 2;   // 0..1  (M)
  const int wc   = wave & 3;    // 0..3  (N)
  const int l15  = lane & 15;
  const int quad = lane >> 4;
  const int m0 = blockIdx.y * 256;
  const int n0 = blockIdx.x * 256;
  const int NT = K >> 5;

  float scale = 1.f;
  if (MODE == 2) scale = expf(scale_ptr[0]);

  // ---- staging: pre-swizzled per-lane global source, linear LDS dest ----
  const uint32_t Sl   = (uint32_t)t * 16u;                    // byte slot in 8 KiB chunk
  const uint32_t Ssw  = Sl ^ (((Sl >> 7) & 7u) << 4);         // involution (bits 7-9 -> 4-6)
  const uint32_t srow = Ssw >> 6;                             // 0..127 within chunk
  const uint32_t sk   = ((Ssw >> 4) & 3u) * 8u;               // k offset in shorts
  const short* gA0 = A + (size_t)(m0 + srow) * lda + sk;
  const short* gA1 = A + (size_t)(m0 + 128 + srow) * lda + sk;
  const short* gB0 = B + (size_t)(n0 + srow) * ldb + sk;
  const short* gB1 = B + (size_t)(n0 + 128 + srow) * ldb + sk;
  short* lp = lds_s + t * 8;

#define STAGE_A(kt) { const int tb = ((kt) & 3) << 14; const int kk = (kt) << 5; \
    GLDS(gA0 + kk, lp + tb); GLDS(gA1 + kk, lp + tb + 4096); }
#define STAGE_B(kt) { const int tb = ((kt) & 3) << 14; const int kk = (kt) << 5; \
    GLDS(gB0 + kk, lp + tb + 8192); GLDS(gB1 + kk, lp + tb + 12288); }

  // ---- ds_read offsets (shorts), swizzled, loop-invariant ----
  int offA[8], offB[4];
#pragma unroll
  for (int x = 0; x < 8; ++x) {
    uint32_t S = (uint32_t)((wr * 128 + (x >> 2) * 64 + (x & 3) * 16 + l15) * 64 + quad * 16);
    offA[x] = (int)((S ^ (((S >> 7) & 7u) << 4)) >> 1);
  }
#pragma unroll
  for (int j = 0; j < 4; ++j) {
    uint32_t S = (uint32_t)((wc * 64 + j * 16 + l15) * 64 + quad * 16);
    offB[j] = (int)(((S ^ (((S >> 7) & 7u) << 4)) >> 1) + 8192u);
  }

  f32x4 acc[8][4];
#pragma unroll
  for (int i = 0; i < 8; ++i)
#pragma unroll
    for (int j = 0; j < 4; ++j)
      acc[i][j] = (f32x4){0.f, 0.f, 0.f, 0.f};

  // ---- prologue: stage 3 tiles, wait only for tile 0 ----
  STAGE_A(0); STAGE_B(0);
  if (NT > 1) { STAGE_A(1); STAGE_B(1); }
  if (NT > 2) { STAGE_A(2); STAGE_B(2); }
  if (NT > 2)      asm volatile("s_waitcnt vmcnt(8)" ::: "memory");
  else if (NT > 1) asm volatile("s_waitcnt vmcnt(4)" ::: "memory");
  else             asm volatile("s_waitcnt vmcnt(0)" ::: "memory");
  asm volatile("s_barrier" ::: "memory");

  for (int kt = 0; kt < NT; ++kt) {
    const short* tile = lds_s + ((kt & 3) << 14);
    short8 a[4], b[4];
    // ---- phase 1: A-half 0 x all B ----
    if (kt + 3 < NT) { STAGE_A(kt + 3); }
#pragma unroll
    for (int j = 0; j < 4; ++j) b[j] = *(const short8*)(tile + offB[j]);
#pragma unroll
    for (int i = 0; i < 4; ++i) a[i] = *(const short8*)(tile + offA[i]);
    __builtin_amdgcn_s_setprio(1);
#pragma unroll
    for (int i = 0; i < 4; ++i)
#pragma unroll
      for (int j = 0; j < 4; ++j)
        acc[i][j] = __builtin_amdgcn_mfma_f32_16x16x32_bf16(a[i], b[j], acc[i][j], 0, 0, 0);
    __builtin_amdgcn_s_setprio(0);
    asm volatile("s_barrier" ::: "memory");   // phase-lock (no correctness role)
    // ---- phase 2: A-half 1 x all B (b[] held in regs) ----
    if (kt + 3 < NT) { STAGE_B(kt + 3); }
#pragma unroll
    for (int i = 0; i < 4; ++i) a[i] = *(const short8*)(tile + offA[4 + i]);
    __builtin_amdgcn_s_setprio(1);
#pragma unroll
    for (int i = 0; i < 4; ++i)
#pragma unroll
      for (int j = 0; j < 4; ++j)
        acc[4 + i][j] = __builtin_amdgcn_mfma_f32_16x16x32_bf16(a[i], b[j], acc[4 + i][j], 0, 0, 0);
    __builtin_amdgcn_s_setprio(0);
    // ---- tile boundary: counted vmcnt so prefetch stays in flight; lgkmcnt(0)
    // pins all my ds_reads of this tile before anyone may clobber ring slots.
    if (kt < NT - 1) {
      if (kt + 3 < NT)      asm volatile("s_waitcnt vmcnt(8) lgkmcnt(0)" ::: "memory");
      else if (kt + 2 < NT) asm volatile("s_waitcnt vmcnt(4) lgkmcnt(0)" ::: "memory");
      else                  asm volatile("s_waitcnt vmcnt(0) lgkmcnt(0)" ::: "memory");
      asm volatile("s_barrier" ::: "memory");
    }
  }
#undef STAGE_A
#undef STAGE_B

  // ---- epilogue ----
#pragma unroll
  for (int mh = 0; mh < 2; ++mh) {
#pragma unroll
    for (int i = 0; i < 4; ++i) {
      const int rowb = m0 + wr * 128 + mh * 64 + i * 16 + quad * 4;
#pragma unroll
      for (int j = 0; j < 4; ++j) {
        const int col = n0 + wc * 64 + j * 16 + l15;
        const float bv = (MODE == 2) ? 0.f : bias[col];
        f32x4 v = acc[mh * 4 + i][j];
#pragma unroll
        for (int r = 0; r < 4; ++r) {
          float x = v[r];
          if (MODE == 0) {
            ((short*)C)[(size_t)(rowb + r) * ldc + col] = f2bf(gelu_exact(x + bv));
          } else if (MODE == 1) {
            ((float*)C)[(size_t)(rowb + r) * ldc + col] = x + bv;
          } else {
            ((float*)C)[(size_t)(rowb + r) * ldc + col] = x * scale;
          }
        }
      }
    }
  }
}

// ---------------------------------------------------------------------------
// Shared GEMM body (128x128, m97-style) — kept for the small GEMMs
// (proj N=512, resid N=768: too few 256^2 blocks to fill the chip).
// ---------------------------------------------------------------------------
template <int MODE>
__device__ __forceinline__ void gemm_body(
    const short* __restrict__ A, int lda,
    const short* __restrict__ B, int ldb,
    void* __restrict__ C, int ldc, int K,
    const float* __restrict__ bias, float scale,
    int m0, int n0)
{
  __shared__ short sA[4096];  // 128 x 32
  __shared__ short sB[4096];
  const int t    = threadIdx.x;
  const int lane = t & 63;
  const int wave = t >> 6;
  const int wm = (wave >> 1) * 64;
  const int wn = (wave & 1) * 64;
  const int l15  = lane & 15;
  const int quad = lane >> 4;

  f32x4 acc[4][4];
#pragma unroll
  for (int i = 0; i < 4; ++i)
#pragma unroll
    for (int j = 0; j < 4; ++j)
      acc[i][j] = (f32x4){0.f, 0.f, 0.f, 0.f};

  const int rr = t >> 2;
  const int cc = (t & 3) * 8;
  const short* gA0 = A + (size_t)(m0 + rr) * lda + cc;
  const short* gA1 = A + (size_t)(m0 + 64 + rr) * lda + cc;
  const short* gB0 = B + (size_t)(n0 + rr) * ldb + cc;
  const short* gB1 = B + (size_t)(n0 + 64 + rr) * ldb + cc;
  short* lA0 = sA + t * 8;
  short* lA1 = sA + 2048 + t * 8;
  short* lB0 = sB + t * 8;
  short* lB1 = sB + 2048 + t * 8;

  for (int k0 = 0; k0 < K; k0 += 32) {
    GLDS(gA0 + k0, lA0);
    GLDS(gA1 + k0, lA1);
    GLDS(gB0 + k0, lB0);
    GLDS(gB1 + k0, lB1);
    __syncthreads();
    short8 af[4], bfr[4];
#pragma unroll
    for (int i = 0; i < 4; ++i)
      af[i] = *(const short8*)(sA + (wm + i * 16 + l15) * 32 + quad * 8);
#pragma unroll
    for (int j = 0; j < 4; ++j)
      bfr[j] = *(const short8*)(sB + (wn + j * 16 + l15) * 32 + quad * 8);
#pragma unroll
    for (int i = 0; i < 4; ++i)
#pragma unroll
      for (int j = 0; j < 4; ++j)
        acc[i][j] = __builtin_amdgcn_mfma_f32_16x16x32_bf16(af[i], bfr[j], acc[i][j], 0, 0, 0);
    __syncthreads();
  }

#pragma unroll
  for (int i = 0; i < 4; ++i) {
#pragma unroll
    for (int j = 0; j < 4; ++j) {
      const int col = n0 + wn + j * 16 + l15;
      float bv = (MODE == 2) ? 0.f : bias[col];
#pragma unroll
      for (int r = 0; r < 4; ++r) {
        const int row = m0 + wm + i * 16 + quad * 4 + r;  // C/D: col=lane&15, row=quad*4+reg
        float v = acc[i][j][r];
        if (MODE == 0) {
          v = gelu_exact(v + bv);
          ((short*)C)[(size_t)row * ldc + col] = f2bf(v);
        } else if (MODE == 1) {
          ((float*)C)[(size_t)row * ldc + col] = v + bv;
        } else {
          ((float*)C)[(size_t)row * ldc + col] = v * scale;
        }
      }
    }
  }
}

template <int MODE>
__global__ __launch_bounds__(256, 2)
void gemm_bt(const short* __restrict__ A, int lda,
             const short* __restrict__ B, int ldb,
             void* __restrict__ C, int ldc, int K,
             const float* __restrict__ bias,
             const float* __restrict__ scale_ptr)
{
  float scale = 1.f;
  if (MODE == 2) scale = expf(scale_ptr[0]);
  gemm_body<MODE>(A, lda, B, ldb, C, ldc, K, bias, scale,
                  blockIdx.y * 128, blockIdx.x * 128);
}

// both projections in one launch: z=0 -> text@Wt.T (cols 0..511),
// z=1 -> image@Wi.T (cols 512..1023); C is comb [B,1024] bf16
__global__ __launch_bounds__(256, 2)
void gemm_proj(const short* __restrict__ textb, const short* __restrict__ imgb,
               const short* __restrict__ Wtb, const short* __restrict__ Wib,
               const float* __restrict__ bt, const float* __restrict__ bi,
               short* __restrict__ comb)
{
  const int z = blockIdx.z;
  const short* A = z ? imgb : textb;
  const short* B = z ? Wib : Wtb;
  const float* bias = z ? bi : bt;
  short* C = comb + (z ? 512 : 0);
  gemm_body<0>(A, FDIM, B, FDIM, C, 1024, FDIM, bias, 1.f,
               blockIdx.y * 128, blockIdx.x * 128);
}

// ---------------------------------------------------------------------------
// One kernel for ALL f32->bf16 conversions + bias concat. Flat grid over
// vec4 units with hardcoded segment boundaries.
// ---------------------------------------------------------------------------
#define SEG0 1572864u   // text   (8192*768/4)
#define SEG1 3145728u   // image
#define SEG2 3244032u   // Wt     (512*768/4)
#define SEG3 3342336u   // Wi
#define SEG4 4390912u   // exp_W  (4*1024*1024/4)
#define SEG5 4653056u   // ds_W1  (1024*1024/4)
#define SEG6 4718592u   // rt_W1  (256*1024/4)
#define SEG7 4915200u   // out_W  (768*1024/4)
#define SEG8 4916544u   // bias concat (5376/4)

__global__ __launch_bounds__(256)
void prep_all(const float* __restrict__ text, const float* __restrict__ image,
              const float* __restrict__ Wt, const float* __restrict__ Wi,
              const float* __restrict__ exp_W, const float* __restrict__ ds_W1,
              const float* __restrict__ rt_W1, const float* __restrict__ out_W,
              const float* __restrict__ exp_b, const float* __restrict__ ds_b1,
              const float* __restrict__ rt_b1,
              short* __restrict__ textb, short* __restrict__ imgb,
              short* __restrict__ Wtb, short* __restrict__ Wib,
              short* __restrict__ Bcat, short* __restrict__ outWb,
              float* __restrict__ biascat)
{
  const uint32_t i = blockIdx.x * 256 + threadIdx.x;
  if (i >= SEG8) return;
  if (i >= SEG7) {  // bias concat (f32 -> f32)
    const uint32_t j = (i - SEG7) * 4;
#pragma unroll
    for (int k = 0; k < 4; ++k) {
      uint32_t idx = j + k;
      float v;
      if (idx < 4096)      v = exp_b[idx];
      else if (idx < 5120) v = ds_b1[idx - 4096];
      else                 v = rt_b1[idx - 5120];
      biascat[idx] = v;
    }
    return;
  }
  const float* s;
  short* d;
  uint32_t j;
  if (i < SEG1) {
    if (i < SEG0) { j = i;        s = text;  d = textb; }
    else          { j = i - SEG0; s = image; d = imgb;  }
  } else if (i < SEG3) {
    if (i < SEG2) { j = i - SEG1; s = Wt; d = Wtb; }
    else          { j = i - SEG2; s = Wi; d = Wib; }
  } else if (i < SEG5) {
    if (i < SEG4) { j = i - SEG3; s = exp_W; d = Bcat; }
    else          { j = i - SEG4; s = ds_W1; d = Bcat + (size_t)4096 * 1024; }
  } else {
    if (i < SEG6) { j = i - SEG5; s = rt_W1; d = Bcat + (size_t)5120 * 1024; }
    else          { j = i - SEG6; s = out_W; d = outWb; }
  }
  float4 v = ((const float4*)s)[j];
  short4v o = { f2bf(v.x), f2bf(v.y), f2bf(v.z), f2bf(v.w) };
  ((short4v*)d)[j] = o;
}

// ---------------------------------------------------------------------------
// Fused router + ds scalar + expert mixing. One block (256 thr) per row.
// ---------------------------------------------------------------------------
__global__ __launch_bounds__(256)
void moe_mix(const short* __restrict__ Hall,
             const float* __restrict__ rt_W2, const float* __restrict__ rt_b2,
             const float* __restrict__ ds_W2, const float* __restrict__ ds_b2,
             float* __restrict__ out_probs, float* __restrict__ out_ds,
             short* __restrict__ fused)
{
  const int b = blockIdx.x;
  const int t = threadIdx.x;
  const int lane = t & 63;
  const int wave = t >> 6;
  const short* h = Hall + (size_t)b * NCAT;

  float rv = bf2f(h[5120 + t]);
  float p0 = rv * rt_W2[t];
  float p1 = rv * rt_W2[256 + t];
  float p2 = rv * rt_W2[512 + t];
  float p3 = rv * rt_W2[768 + t];
  float dd = 0.f;
#pragma unroll
  for (int k = 0; k < 4; ++k)
    dd += bf2f(h[4096 + k * 256 + t]) * ds_W2[k * 256 + t];

#pragma unroll
  for (int off = 32; off; off >>= 1) {
    p0 += __shfl_xor(p0, off);
    p1 += __shfl_xor(p1, off);
    p2 += __shfl_xor(p2, off);
    p3 += __shfl_xor(p3, off);
    dd += __shfl_xor(dd, off);
  }
  __shared__ float red[5][4];
  __shared__ float bc[5];
  if (lane == 0) {
    red[0][wave] = p0; red[1][wave] = p1; red[2][wave] = p2;
    red[3][wave] = p3; red[4][wave] = dd;
  }
  __syncthreads();
  if (t == 0) {
    float l0 = red[0][0] + red[0][1] + red[0][2] + red[0][3] + rt_b2[0];
    float l1 = red[1][0] + red[1][1] + red[1][2] + red[1][3] + rt_b2[1];
    float l2 = red[2][0] + red[2][1] + red[2][2] + red[2][3] + rt_b2[2];
    float l3 = red[3][0] + red[3][1] + red[3][2] + red[3][3] + rt_b2[3];
    float d  = red[4][0] + red[4][1] + red[4][2] + red[4][3] + ds_b2[0];
    float mx = fmaxf(fmaxf(l0, l1), fmaxf(l2, l3));
    float e0 = expf(l0 - mx), e1 = expf(l1 - mx);
    float e2 = expf(l2 - mx), e3 = expf(l3 - mx);
    float inv = 1.f / (e0 + e1 + e2 + e3);
    bc[0] = e0 * inv; bc[1] = e1 * inv; bc[2] = e2 * inv; bc[3] = e3 * inv;
    bc[4] = 1.f / (1.f + expf(-d));
    out_probs[b * 4 + 0] = bc[0];
    out_probs[b * 4 + 1] = bc[1];
    out_probs[b * 4 + 2] = bc[2];
    out_probs[b * 4 + 3] = bc[3];
    out_ds[b] = bc[4];
  }
  __syncthreads();
  const float q0 = bc[0], q1 = bc[1], q2 = bc[2], q3 = bc[3];
  short* fr = fused + (size_t)b * 1024;
#pragma unroll
  for (int c = t; c < 1024; c += 256) {
    float v = q0 * bf2f(h[c])        + q1 * bf2f(h[1024 + c])
            + q2 * bf2f(h[2048 + c]) + q3 * bf2f(h[3072 + c]);
    fr[c] = f2bf(v);
  }
}

// ---------------------------------------------------------------------------
// Both normalizes in one launch.
// ---------------------------------------------------------------------------
__global__ __launch_bounds__(256)
void normalize_both(const float* __restrict__ text, const float* __restrict__ image,
                    const float* __restrict__ ds, const float* __restrict__ resid,
                    const float* __restrict__ target,
                    short* __restrict__ pred, short* __restrict__ tgtb)
{
  const int bb = blockIdx.x;
  const int t = threadIdx.x;
  float o0, o1, o2;
  short* d;
  if (bb < BDIM) {
    const float dv = ds[bb];
    const float* tx = text + (size_t)bb * FDIM;
    const float* im = image + (size_t)bb * FDIM;
    const float* s  = resid + (size_t)bb * FDIM;
    o0 = dv * tx[t]       + (1.f - dv) * im[t]       + s[t];
    o1 = dv * tx[t + 256] + (1.f - dv) * im[t + 256] + s[t + 256];
    o2 = dv * tx[t + 512] + (1.f - dv) * im[t + 512] + s[t + 512];
    d = pred + (size_t)bb * FDIM;
  } else {
    const int b = bb - BDIM;
    const float* s = target + (size_t)b * FDIM;
    o0 = s[t]; o1 = s[t + 256]; o2 = s[t + 512];
    d = tgtb + (size_t)b * FDIM;
  }
  float ss = o0 * o0 + o1 * o1 + o2 * o2;
  __shared__ float red[4];
#pragma unroll
  for (int off = 32; off; off >>= 1) ss += __shfl_xor(ss, off);
  if ((t & 63) == 0) red[t >> 6] = ss;
  __syncthreads();
  const float tot = red[0] + red[1] + red[2] + red[3];
  const float rn = 1.f / fmaxf(sqrtf(tot), 1e-12f);
  d[t]       = f2bf(o0 * rn);
  d[t + 256] = f2bf(o1 * rn);
  d[t + 512] = f2bf(o2 * rn);
}

// ---------------------------------------------------------------------------
extern "C" void kernel_launch(void* const* d_in, const int* in_sizes, int n_in,
                              void* d_out, int out_size, void* d_ws, size_t ws_size,
                              hipStream_t stream) {
  const float* image  = (const float*)d_in[0];
  const float* text   = (const float*)d_in[1];
  const float* target = (const float*)d_in[2];
  const float* Wt     = (const float*)d_in[3];
  const float* bt     = (const float*)d_in[4];
  const float* Wi     = (const float*)d_in[5];
  const float* bi     = (const float*)d_in[6];
  const float* ds_W1  = (const float*)d_in[7];
  const float* ds_b1  = (const float*)d_in[8];
  const float* ds_W2  = (const float*)d_in[9];
  const float* ds_b2  = (const float*)d_in[10];
  const float* exp_W  = (const float*)d_in[11];
  const float* exp_b  = (const float*)d_in[12];
  const float* rt_W1  = (const float*)d_in[13];
  const float* rt_b1  = (const float*)d_in[14];
  const float* rt_W2  = (const float*)d_in[15];
  const float* rt_b2  = (const float*)d_in[16];
  const float* out_W  = (const float*)d_in[17];
  const float* out_b  = (const float*)d_in[18];
  const float* logit_scale = (const float*)d_in[19];

  char* ws = (char*)d_ws;
  short* comb  = (short*)ws;  ws += (size_t)BDIM * 1024 * 2;
  short* Hall  = (short*)ws;  ws += (size_t)BDIM * NCAT * 2;
  short* fused = (short*)ws;  ws += (size_t)BDIM * 1024 * 2;
  float* resid = (float*)ws;  ws += (size_t)BDIM * FDIM * 4;
  short* pred  = (short*)ws;  ws += (size_t)BDIM * FDIM * 2;
  short* tgtb  = (short*)ws;  ws += (size_t)TDIM * FDIM * 2;
  short* textb = (short*)ws;  ws += (size_t)BDIM * FDIM * 2;
  short* imgb  = (short*)ws;  ws += (size_t)BDIM * FDIM * 2;
  short* Wtb   = (short*)ws;  ws += (size_t)PDIM * FDIM * 2;
  short* Wib   = (short*)ws;  ws += (size_t)PDIM * FDIM * 2;
  short* outWb = (short*)ws;  ws += (size_t)FDIM * HDIM * 2;
  short* Bcat  = (short*)ws;  ws += (size_t)NCAT * HDIM * 2;
  float* biascat = (float*)ws; ws += (size_t)NCAT * 4;

  float* out_logits = (float*)d_out;
  float* out_ds     = out_logits + (size_t)BDIM * TDIM;
  float* out_probs  = out_ds + BDIM;

  // 1. all conversions + bias concat in one launch
  prep_all<<<(SEG8 + 255) / 256, 256, 0, stream>>>(
      text, image, Wt, Wi, exp_W, ds_W1, rt_W1, out_W,
      exp_b, ds_b1, rt_b1,
      textb, imgb, Wtb, Wib, Bcat, outWb, biascat);

  dim3 blk(256);
  // 2. comb = [gelu(text@Wt.T+bt), gelu(image@Wi.T+bi)] -> bf16 [B,1024]
  gemm_proj<<<dim3(PDIM / 128, BDIM / 128, 2), blk, 0, stream>>>(
      textb, imgb, Wtb, Wib, bt, bi, comb);
  // 3. Hall = gelu(comb @ [exp_W;ds_W1;rt_W1].T + bias) -> bf16 [B,5376]
  //    256^2 deep-pipelined tile (NCAT = 21*256, K = 32*32)
  gemm256<0><<<dim3(NCAT / 256, BDIM / 256), dim3(512), 0, stream>>>(
      comb, 1024, Bcat, 1024, Hall, NCAT, 1024, biascat, nullptr);
  // 4. router probs + ds + fused hidden (single pass over Hall)
  moe_mix<<<BDIM, 256, 0, stream>>>(Hall, rt_W2, rt_b2, ds_W2, ds_b2,
                                    out_probs, out_ds, fused);
  // 5. residual = fused @ out_W.T + out_b -> f32 [B,768]
  gemm_bt<1><<<dim3(FDIM / 128, BDIM / 128), blk, 0, stream>>>(
      fused, 1024, outWb, 1024, resid, FDIM, 1024, out_b, nullptr);
  // 6. pred + tgt normalize in one launch
  normalize_both<<<BDIM + TDIM, 256, 0, stream>>>(
      text, image, out_ds, resid, target, pred, tgtb);
  // 7. logits = exp(logit_scale) * pred @ tgt.T -> f32 [B,T]
  //    256^2 deep-pipelined tile (8192 = 32*256, K = 24*32)
  gemm256<2><<<dim3(TDIM / 256, BDIM / 256), dim3(512), 0, stream>>>(
      pred, FDIM, tgtb, FDIM, out_logits, TDIM, FDIM, nullptr, logit_scale);
}